// Round 16
// baseline (1086.078 us; speedup 1.0000x reference)
//
#include <hip/hip_runtime.h>
#include <hip/hip_bf16.h>

static const int S    = 16640;  // padded sequence (65*256)
static const int PADR = 255;    // zero rows prepended inside attention
static const int NT   = 16385;  // tokens incl cls
static const int CH   = 512;    // hidden dim

typedef unsigned short u16;
typedef __attribute__((ext_vector_type(8))) short short8_t;
typedef __attribute__((ext_vector_type(4))) float float4_t;

__device__ __forceinline__ float b2f(u16 x) {
  union { unsigned u; float f; } t; t.u = (unsigned)x << 16; return t.f;
}
__device__ __forceinline__ u16 f2b(float x) {
  union { float f; unsigned u; } t; t.f = x;
  unsigned r = t.u + 0x7fff + ((t.u >> 16) & 1);
  return (u16)(r >> 16);
}

// async global->LDS, 16B per lane; LDS dest is wave-uniform base + lane*16
__device__ __forceinline__ void gload_lds16(const u16* g, u16* l) {
  __builtin_amdgcn_global_load_lds(
      (const __attribute__((address_space(1))) unsigned int*)(g),
      (__attribute__((address_space(3))) unsigned int*)(l), 16, 0, 0);
}

__device__ __forceinline__ float warpSum(float v) {
#pragma unroll
  for (int off = 32; off; off >>= 1) v += __shfl_xor(v, off);
  return v;
}
__device__ __forceinline__ float warpMax(float v) {
#pragma unroll
  for (int off = 32; off; off >>= 1) v = fmaxf(v, __shfl_xor(v, off));
  return v;
}
__device__ __forceinline__ float blockSum(float v) {
  __shared__ float sm[8];
  int lane = threadIdx.x & 63, wv = threadIdx.x >> 6;
  v = warpSum(v);
  __syncthreads();
  if (lane == 0) sm[wv] = v;
  __syncthreads();
  float t = 0.f;
  int nw = blockDim.x >> 6;
  for (int i = 0; i < nw; i++) t += sm[i];
  return t;
}
__device__ __forceinline__ float blockMax(float v) {
  __shared__ float sm[8];
  int lane = threadIdx.x & 63, wv = threadIdx.x >> 6;
  v = warpMax(v);
  __syncthreads();
  if (lane == 0) sm[wv] = v;
  __syncthreads();
  float t = -1e30f;
  int nw = blockDim.x >> 6;
  for (int i = 0; i < nw; i++) t = fmaxf(t, sm[i]);
  return t;
}

// ---------------------------------------------------------------------------
__global__ __launch_bounds__(256) void cvt_f2b(const float* __restrict__ in,
                                               u16* __restrict__ out, long n) {
  long i = ((long)blockIdx.x * 256 + threadIdx.x) * 4;
  if (i + 3 < n) {
    float4 v = *(const float4*)(in + i);
    out[i] = f2b(v.x); out[i + 1] = f2b(v.y); out[i + 2] = f2b(v.z); out[i + 3] = f2b(v.w);
  } else {
    for (long j = i; j < n; j++) out[j] = f2b(in[j]);
  }
}

// WmT[head][n(64)][k(256)] bf16 <- Wm[head][k(256)][n(64)] f32
__global__ __launch_bounds__(256) void wm_transpose(const float* __restrict__ Wm,
                                                    u16* __restrict__ WmT) {
  int n = blockIdx.x, head = blockIdx.y, k = threadIdx.x;
  WmT[((long)head * 64 + n) * 256 + k] = f2b(Wm[(long)head * 16384 + k * 64 + n]);
}

// ---------------------------------------------------------------------------
// Generalized gload_lds MFMA GEMM, BK=64, 2-phase double-buffered pipeline:
// issue next K-tile's global_load_lds into buf^1 BEFORE computing buf, one
// barrier per tile (drains vmcnt + fences reads). Linear LDS (row = 128B)
// + 3-bit XOR source/read swizzle. XCD-bijective block swizzle (T1).
// 128x128 tile, K%64==0, lda/ldb%8==0. A rows beyond M may be read
// (must be in allocation); C-writes masked.
//  EPI 0: C = alpha*acc + bias? + beta*C (f32)
//  EPI 1: C = relu(acc + bias) (f32)
//  EPI 2: qkv head-split bf16 store (q scaled by alpha)
template <int EPI>
__global__ __launch_bounds__(256) void mfma_gemm_g(
    const u16* __restrict__ A, const u16* __restrict__ B, float* __restrict__ C,
    const float* __restrict__ bias, int M, int N, int K,
    int lda, int ldb, int ldc, float alpha, float beta,
    u16* __restrict__ q_o, u16* __restrict__ k_o, u16* __restrict__ v_o, long s64)
{
  __shared__ u16 As[2][128 * 64];
  __shared__ u16 Bs[2][128 * 64];
  const int tid = threadIdx.x;
  const int nwg = gridDim.x * gridDim.y;
  int lid = blockIdx.y * gridDim.x + blockIdx.x;
  {
    const int qq = nwg >> 3, rr = nwg & 7;
    const int xcd = lid & 7, loc = lid >> 3;
    lid = (xcd < rr ? xcd * (qq + 1) : rr * (qq + 1) + (xcd - rr) * qq) + loc;
  }
  const int m0 = (lid / gridDim.x) * 128, n0 = (lid % gridDim.x) * 128;
  const int wid = tid >> 6, lane = tid & 63;
  const int wr = wid >> 1, wc = wid & 1;
  const int l15 = lane & 15, l16 = lane >> 4;
  const int r8 = lane >> 3;       // 0..7
  const int slot = lane & 7;      // 0..7 (16B slots per 128B row)
  float4_t acc[4][4] = {};

  auto stage = [&](int buf, int k0) {
#pragma unroll
    for (int inst = 0; inst < 4; inst++) {
      const int rbase = wid * 32 + inst * 8;
      const int row = rbase + r8;
      const int gslot = slot ^ ((row >> 1) & 7);
      gload_lds16(A + (long)(m0 + row) * lda + k0 + gslot * 8, &As[buf][rbase * 64]);
      gload_lds16(B + (long)(n0 + row) * ldb + k0 + gslot * 8, &Bs[buf][rbase * 64]);
    }
  };

  const int nt = K >> 6;
  stage(0, 0);
  __syncthreads();
  int cur = 0;
  for (int t = 0; t < nt; t++) {
    if (t + 1 < nt) stage(cur ^ 1, (t + 1) << 6);
#pragma unroll
    for (int kk = 0; kk < 2; kk++) {
      short8_t af[4], bfr[4];
#pragma unroll
      for (int i = 0; i < 4; i++) {
        int row = wr * 64 + i * 16 + l15;
        af[i] = *(const short8_t*)&As[cur][row * 64 + ((((kk << 2) + l16) ^ ((row >> 1) & 7)) << 3)];
        int rowb = wc * 64 + i * 16 + l15;
        bfr[i] = *(const short8_t*)&Bs[cur][rowb * 64 + ((((kk << 2) + l16) ^ ((rowb >> 1) & 7)) << 3)];
      }
#pragma unroll
      for (int i = 0; i < 4; i++)
#pragma unroll
        for (int j = 0; j < 4; j++)
          acc[i][j] = __builtin_amdgcn_mfma_f32_16x16x32_bf16(af[i], bfr[j], acc[i][j], 0, 0, 0);
    }
    __syncthreads();   // drains prefetch (vmcnt) + fences reads of buf[cur]
    cur ^= 1;
  }

#pragma unroll
  for (int mi = 0; mi < 4; mi++) {
#pragma unroll
    for (int ni = 0; ni < 4; ni++) {
#pragma unroll
      for (int j = 0; j < 4; j++) {
        int r = m0 + wr * 64 + mi * 16 + (l16 << 2) + j;
        int c = n0 + wc * 64 + ni * 16 + l15;
        if (r >= M || c >= N) continue;
        float v = acc[mi][ni][j];
        if constexpr (EPI == 0) {
          long idx = (long)r * ldc + c;
          float o = alpha * v;
          if (bias) o += bias[c];
          if (beta != 0.f) o += beta * C[idx];
          C[idx] = o;
        } else if constexpr (EPI == 1) {
          long idx = (long)r * ldc + c;
          C[idx] = fmaxf(v + bias[c], 0.f);
        } else {  // EPI == 2: qkv split
          int sec = c >> 9, hcol = c & 511;
          int head = hcol >> 6, d = hcol & 63;
          u16* dst = (sec == 0) ? q_o : (sec == 1 ? k_o : v_o);
          float o = (sec == 0) ? v * alpha : v;
          dst[(long)head * s64 + (long)r * 64 + d] = f2b(o);
        }
      }
    }
  }
}

// ---------------------------------------------------------------------------
// Newton-Schulz pinv GEMM. 32x32 tile/block, grid (8,8,8).
// PREC=1: bf16 hi/lo split (3 MFMAs, f32-grade). PREC=0: plain bf16 (1 MFMA).
template <int MODE, int PREC>
__global__ __launch_bounds__(256) void pinv_gemm(
    const float* __restrict__ A, const float* __restrict__ B,
    float* __restrict__ C, float* __restrict__ C2, float alpha, float beta)
{
  __shared__ u16 Ah[32][36], Bh[32][36];
  __shared__ u16 Al[PREC ? 32 : 1][36], Bl[PREC ? 32 : 1][36];
  const int tid = threadIdx.x;
  const long zoff = (long)blockIdx.z << 16;
  A += zoff; B += zoff; C += zoff;
  if constexpr (MODE == 3) C2 += zoff;
  const int m0 = blockIdx.y * 32, n0 = blockIdx.x * 32;
  const int wid = tid >> 6, lane = tid & 63;
  const int wr = wid >> 1, wc = wid & 1;
  const int l15 = lane & 15, l16 = lane >> 4;
  const int arow = tid >> 3, acol = (tid & 7) * 4;
  float4_t acc = {};

  for (int k0 = 0; k0 < 256; k0 += 32) {
    {
      float4 va = *(const float4*)(A + (long)(m0 + arow) * 256 + k0 + acol);
      float4 vb = *(const float4*)(B + (long)(k0 + arow) * 256 + n0 + acol);
      float fa[4] = {va.x, va.y, va.z, va.w};
      float fb[4] = {vb.x, vb.y, vb.z, vb.w};
#pragma unroll
      for (int i = 0; i < 4; i++) {
        u16 hi = f2b(fa[i]);
        Ah[arow][acol + i] = hi;
        u16 hj = f2b(fb[i]);
        Bh[acol + i][arow] = hj;
        if constexpr (PREC) {
          Al[arow][acol + i] = f2b(fa[i] - b2f(hi));
          Bl[acol + i][arow] = f2b(fb[i] - b2f(hj));
        }
      }
    }
    __syncthreads();
    short8_t ah = *(const short8_t*)&Ah[wr * 16 + l15][l16 * 8];
    short8_t bh = *(const short8_t*)&Bh[wc * 16 + l15][l16 * 8];
    acc = __builtin_amdgcn_mfma_f32_16x16x32_bf16(ah, bh, acc, 0, 0, 0);
    if constexpr (PREC) {
      short8_t al = *(const short8_t*)&Al[wr * 16 + l15][l16 * 8];
      short8_t bl = *(const short8_t*)&Bl[wc * 16 + l15][l16 * 8];
      acc = __builtin_amdgcn_mfma_f32_16x16x32_bf16(ah, bl, acc, 0, 0, 0);
      acc = __builtin_amdgcn_mfma_f32_16x16x32_bf16(al, bh, acc, 0, 0, 0);
    }
    __syncthreads();
  }

#pragma unroll
  for (int j = 0; j < 4; j++) {
    int r = m0 + wr * 16 + l16 * 4 + j;
    int c = n0 + wc * 16 + l15;
    long idx = (long)r * 256 + c;
    float v = acc[j];
    if constexpr (MODE == 0) {
      C[idx] = alpha * v;
    } else if constexpr (MODE == 3) {
      C[idx] = v;
      C2[idx] = ((r == c) ? beta : 0.f) - v;
    } else {
      C[idx] = ((r == c) ? beta : 0.f) - v;
    }
  }
}

// ---------------------------------------------------------------------------
// Fused a2 = softmax(ql @ kl^T) per head, f32 out. grid (4 row-tiles, 8 heads).
__global__ __launch_bounds__(256) void a2_fused(
    const u16* __restrict__ qlb, const u16* __restrict__ klb,
    float* __restrict__ a2)
{
  __shared__ u16 KW[256 * 72];
  const int tid = threadIdx.x;
  const int w = tid >> 6, lane = tid & 63;
  const int l15 = lane & 15, l16 = lane >> 4;
  const int head = blockIdx.y;
  const int row0 = blockIdx.x * 64 + w * 16;

  const u16* klh = klb + (long)head * 16384;
#pragma unroll
  for (int i = 0; i < 4; i++) {
    int idx = tid + i * 256;
    int row = idx >> 2, seg = (idx & 3) << 4;
    const u16* src = klh + row * 64 + seg;
    *(short8_t*)&KW[row * 72 + seg]     = *(const short8_t*)src;
    *(short8_t*)&KW[row * 72 + seg + 8] = *(const short8_t*)(src + 8);
  }
  short8_t aq[2];
#pragma unroll
  for (int slab = 0; slab < 2; slab++)
    aq[slab] = *(const short8_t*)(qlb + (long)head * 16384 + (long)(row0 + l15) * 64 + slab * 32 + l16 * 8);
  __syncthreads();

  float4_t sacc[16] = {};
#pragma unroll
  for (int nt = 0; nt < 16; nt++)
#pragma unroll
    for (int slab = 0; slab < 2; slab++) {
      short8_t bfr = *(const short8_t*)&KW[(nt * 16 + l15) * 72 + slab * 32 + l16 * 8];
      sacc[nt] = __builtin_amdgcn_mfma_f32_16x16x32_bf16(aq[slab], bfr, sacc[nt], 0, 0, 0);
    }
#pragma unroll
  for (int reg = 0; reg < 4; reg++) {
    float m = -1e30f;
#pragma unroll
    for (int nt = 0; nt < 16; nt++) m = fmaxf(m, sacc[nt][reg]);
#pragma unroll
    for (int mk = 1; mk <= 8; mk <<= 1) m = fmaxf(m, __shfl_xor(m, mk));
    float s = 0.f;
#pragma unroll
    for (int nt = 0; nt < 16; nt++) { float e = __expf(sacc[nt][reg] - m); sacc[nt][reg] = e; s += e; }
#pragma unroll
    for (int mk = 1; mk <= 8; mk <<= 1) s += __shfl_xor(s, mk);
    float rcp = 1.f / s;
#pragma unroll
    for (int nt = 0; nt < 16; nt++)
      a2[(long)head * 65536 + (long)(row0 + 4 * l16 + reg) * 256 + nt * 16 + l15] =
          sacc[nt][reg] * rcp;
  }
}

// ---------------------------------------------------------------------------
// Fused a1 path (LDS-staged), bf16 output into Fb
__global__ __launch_bounds__(256) void attn_a1(
    const u16* __restrict__ qb, const u16* __restrict__ klb,
    const u16* __restrict__ WmT, u16* __restrict__ Fb, long s64)
{
  __shared__ u16 KW[256 * 72];   // 36.9 KB
  __shared__ u16 Ps[64 * 136];   // 17.4 KB
  const int tid = threadIdx.x;
  const int w = tid >> 6, lane = tid & 63;
  const int l15 = lane & 15, l16 = lane >> 4;
  const int head = blockIdx.y;
  const int row0 = blockIdx.x * 64 + w * 16;

  const u16* klh = klb + (long)head * 16384;
#pragma unroll
  for (int i = 0; i < 4; i++) {
    int idx = tid + i * 256;
    int row = idx >> 2, seg = (idx & 3) << 4;
    const u16* src = klh + row * 64 + seg;
    *(short8_t*)&KW[row * 72 + seg]     = *(const short8_t*)src;
    *(short8_t*)&KW[row * 72 + seg + 8] = *(const short8_t*)(src + 8);
  }
  short8_t aq[2];
#pragma unroll
  for (int slab = 0; slab < 2; slab++)
    aq[slab] = *(const short8_t*)(qb + (long)head * s64 + (long)(row0 + l15) * 64 + slab * 32 + l16 * 8);
  __syncthreads();

  float4_t sacc[16] = {};
#pragma unroll
  for (int nt = 0; nt < 16; nt++)
#pragma unroll
    for (int slab = 0; slab < 2; slab++) {
      short8_t bfr = *(const short8_t*)&KW[(nt * 16 + l15) * 72 + slab * 32 + l16 * 8];
      sacc[nt] = __builtin_amdgcn_mfma_f32_16x16x32_bf16(aq[slab], bfr, sacc[nt], 0, 0, 0);
    }
  float rcp[4];
#pragma unroll
  for (int reg = 0; reg < 4; reg++) {
    float m = -1e30f;
#pragma unroll
    for (int nt = 0; nt < 16; nt++) m = fmaxf(m, sacc[nt][reg]);
#pragma unroll
    for (int mk = 1; mk <= 8; mk <<= 1) m = fmaxf(m, __shfl_xor(m, mk));
    float s = 0.f;
#pragma unroll
    for (int nt = 0; nt < 16; nt++) { float e = __expf(sacc[nt][reg] - m); sacc[nt][reg] = e; s += e; }
#pragma unroll
    for (int mk = 1; mk <= 8; mk <<= 1) s += __shfl_xor(s, mk);
    rcp[reg] = 1.f / s;
  }
  __syncthreads();

  const u16* wmh = WmT + (long)head * 16384;
#pragma unroll
  for (int i = 0; i < 4; i++) {
    int idx = tid + i * 256;
    int row = idx >> 4, seg = (idx & 15) << 4;
    const u16* src = wmh + row * 256 + seg;
    *(short8_t*)&KW[row * 264 + seg]     = *(const short8_t*)src;
    *(short8_t*)&KW[row * 264 + seg + 8] = *(const short8_t*)(src + 8);
  }
#pragma unroll
  for (int nt = 0; nt < 8; nt++)
#pragma unroll
    for (int reg = 0; reg < 4; reg++)
      Ps[(w * 16 + 4 * l16 + reg) * 136 + nt * 16 + l15] = f2b(sacc[nt][reg]);
  __syncthreads();

  float4_t oacc[4] = {};
#pragma unroll
  for (int ks = 0; ks < 4; ks++) {
    short8_t pa = *(const short8_t*)&Ps[(w * 16 + l15) * 136 + ks * 32 + l16 * 8];
#pragma unroll
    for (int vt = 0; vt < 4; vt++) {
      short8_t bv = *(const short8_t*)&KW[(vt * 16 + l15) * 264 + ks * 32 + l16 * 8];
      oacc[vt] = __builtin_amdgcn_mfma_f32_16x16x32_bf16(pa, bv, oacc[vt], 0, 0, 0);
    }
  }
#pragma unroll
  for (int nt = 8; nt < 16; nt++)
#pragma unroll
    for (int reg = 0; reg < 4; reg++)
      Ps[(w * 16 + 4 * l16 + reg) * 136 + (nt - 8) * 16 + l15] = f2b(sacc[nt][reg]);
#pragma unroll
  for (int ks = 4; ks < 8; ks++) {
    short8_t pa = *(const short8_t*)&Ps[(w * 16 + l15) * 136 + (ks - 4) * 32 + l16 * 8];
#pragma unroll
    for (int vt = 0; vt < 4; vt++) {
      short8_t bv = *(const short8_t*)&KW[(vt * 16 + l15) * 264 + ks * 32 + l16 * 8];
      oacc[vt] = __builtin_amdgcn_mfma_f32_16x16x32_bf16(pa, bv, oacc[vt], 0, 0, 0);
    }
  }
#pragma unroll
  for (int vt = 0; vt < 4; vt++)
#pragma unroll
    for (int reg = 0; reg < 4; reg++) {
      int r = row0 + 4 * l16 + reg;
      Fb[(long)r * CH + head * 64 + vt * 16 + l15] = f2b(oacc[vt][reg] * rcp[reg]);
    }
}

// ---------------------------------------------------------------------------
// Split-K fused a3@v with K and V both LDS-staged.
__global__ __launch_bounds__(256) void attn_a3v_split(
    const u16* __restrict__ qlb, const u16* __restrict__ kb,
    const u16* __restrict__ vb,
    float* __restrict__ pm, float* __restrict__ pl, float* __restrict__ poacc,
    long s64)
{
  __shared__ u16 Vt[64][136];
  __shared__ u16 Kt[128 * 72];
  __shared__ u16 Ps[4][16][136];
  const int tid = threadIdx.x;
  const int w = tid >> 6, lane = tid & 63;
  const int l15 = lane & 15, l16 = lane >> 4;
  const int head = blockIdx.y;
  const int split = blockIdx.z;
  const int row0 = blockIdx.x * 64 + w * 16;

  short8_t aq[2];
#pragma unroll
  for (int slab = 0; slab < 2; slab++)
    aq[slab] = *(const short8_t*)(qlb + (long)head * 16384 + (long)(row0 + l15) * 64 + slab * 32 + l16 * 8);

  float m[4], l[4];
  float4_t oacc[4] = {};
#pragma unroll
  for (int r = 0; r < 4; r++) { m[r] = -1e30f; l[r] = 0.f; }

  const u16* kh = kb + (long)head * s64;
  const u16* vh = vb + (long)head * s64;
  const int vrow = tid >> 1, vhalf = (tid & 1) * 32;

  const int kt0 = split * 10;
  for (int kt = kt0; kt < kt0 + 10; kt++) {
    const int j0 = kt * 128;
    __syncthreads();
    {
      const u16* src = vh + (long)(j0 + vrow) * 64 + vhalf;
#pragma unroll
      for (int i = 0; i < 32; i++) Vt[vhalf + i][vrow] = src[i];
    }
#pragma unroll
    for (int i = 0; i < 2; i++) {
      int idx = tid + i * 256;
      int row = idx >> 2, seg = (idx & 3) << 4;
      const u16* src = kh + (long)(j0 + row) * 64 + seg;
      *(short8_t*)&Kt[row * 72 + seg]     = *(const short8_t*)src;
      *(short8_t*)&Kt[row * 72 + seg + 8] = *(const short8_t*)(src + 8);
    }
    __syncthreads();
    float4_t sacc[8] = {};
#pragma unroll
    for (int nt = 0; nt < 8; nt++)
#pragma unroll
      for (int slab = 0; slab < 2; slab++) {
        short8_t bfr = *(const short8_t*)&Kt[(nt * 16 + l15) * 72 + slab * 32 + l16 * 8];
        sacc[nt] = __builtin_amdgcn_mfma_f32_16x16x32_bf16(aq[slab], bfr, sacc[nt], 0, 0, 0);
      }
    float scale[4];
#pragma unroll
    for (int reg = 0; reg < 4; reg++) {
      float tm = -1e30f;
#pragma unroll
      for (int nt = 0; nt < 8; nt++) tm = fmaxf(tm, sacc[nt][reg]);
#pragma unroll
      for (int mk = 1; mk <= 8; mk <<= 1) tm = fmaxf(tm, __shfl_xor(tm, mk));
      float nm = fmaxf(m[reg], tm);
      scale[reg] = __expf(m[reg] - nm);
      m[reg] = nm;
      float ts = 0.f;
#pragma unroll
      for (int nt = 0; nt < 8; nt++) {
        float e = __expf(sacc[nt][reg] - nm);
        sacc[nt][reg] = e; ts += e;
      }
#pragma unroll
      for (int mk = 1; mk <= 8; mk <<= 1) ts += __shfl_xor(ts, mk);
      l[reg] = l[reg] * scale[reg] + ts;
#pragma unroll
      for (int vt = 0; vt < 4; vt++) oacc[vt][reg] *= scale[reg];
    }
#pragma unroll
    for (int nt = 0; nt < 8; nt++)
#pragma unroll
      for (int reg = 0; reg < 4; reg++)
        Ps[w][4 * l16 + reg][nt * 16 + l15] = f2b(sacc[nt][reg]);
#pragma unroll
    for (int ks = 0; ks < 4; ks++) {
      short8_t pa = *(const short8_t*)&Ps[w][l15][ks * 32 + l16 * 8];
#pragma unroll
      for (int vt = 0; vt < 4; vt++) {
        short8_t bv = *(const short8_t*)&Vt[vt * 16 + l15][ks * 32 + l16 * 8];
        oacc[vt] = __builtin_amdgcn_mfma_f32_16x16x32_bf16(pa, bv, oacc[vt], 0, 0, 0);
      }
    }
  }
#pragma unroll
  for (int reg = 0; reg < 4; reg++) {
    int r = row0 + 4 * l16 + reg;
    long pidx = ((long)(head * 13 + split) << 8) + r;
    if (l15 == 0) { pm[pidx] = m[reg]; pl[pidx] = l[reg]; }
#pragma unroll
    for (int vt = 0; vt < 4; vt++)
      poacc[(pidx << 6) + vt * 16 + l15] = oacc[vt][reg];
  }
}

// merge split partials
__global__ __launch_bounds__(64) void a3v_merge(const float* __restrict__ pm,
    const float* __restrict__ pl, const float* __restrict__ poacc,
    float* __restrict__ w3v)
{
  int hb = blockIdx.x;
  int head = hb >> 8, row = hb & 255;
  int d = threadIdx.x;
  float M = -1e30f;
  for (int sp = 0; sp < 13; sp++)
    M = fmaxf(M, pm[((long)(head * 13 + sp) << 8) + row]);
  float num = 0.f, den = 0.f;
  for (int sp = 0; sp < 13; sp++) {
    long pidx = ((long)(head * 13 + sp) << 8) + row;
    float sc = __expf(pm[pidx] - M);
    den += pl[pidx] * sc;
    num += poacc[(pidx << 6) + d] * sc;
  }
  w3v[((long)head << 14) + ((long)row << 6) + d] = num / den;
}

// ---------------------------------------------------------------------------
// SIMT f32 tiled matmul (Wm).
template <bool BT, int MODE>
__global__ __launch_bounds__(256) void mm_kernel(
    const float* __restrict__ A, const float* __restrict__ Bm, float* __restrict__ C,
    const float* __restrict__ bias,
    int M, int N, int K, int lda, int ldb, int ldc,
    long sA, long sB, long sC, float alpha, float beta, long s64)
{
  __shared__ float As[16][64];
  __shared__ float Bs[16][64];
  const int bz = blockIdx.z;
  A  += (long)bz * sA;
  Bm += (long)bz * sB;
  C  += (long)bz * sC;
  const int m0 = blockIdx.y * 64, n0 = blockIdx.x * 64;
  const int tid = threadIdx.x;
  const int tm = tid >> 4, tn = tid & 15;
  const int ar = tid >> 2;
  const int ac = (tid & 3) << 2;
  float acc[4][4] = {};
  for (int k0 = 0; k0 < K; k0 += 16) {
#pragma unroll
    for (int i = 0; i < 4; i++) {
      int gm = m0 + ar, gk = k0 + ac + i;
      As[ac + i][ar] = (gm < M && gk < K) ? A[(long)gm * lda + gk] : 0.f;
    }
    if constexpr (BT) {
#pragma unroll
      for (int i = 0; i < 4; i++) {
        int gn = n0 + ar, gk = k0 + ac + i;
        Bs[ac + i][ar] = (gn < N && gk < K) ? Bm[(long)gn * ldb + gk] : 0.f;
      }
    } else {
      int bk = tid >> 4;
      int bn = (tid & 15) << 2;
#pragma unroll
      for (int i = 0; i < 4; i++) {
        int gk = k0 + bk, gn = n0 + bn + i;
        Bs[bk][bn + i] = (gk < K && gn < N) ? Bm[(long)gk * ldb + gn] : 0.f;
      }
    }
    __syncthreads();
#pragma unroll
    for (int kk = 0; kk < 16; kk++) {
      float a[4], b[4];
#pragma unroll
      for (int i = 0; i < 4; i++) { a[i] = As[kk][tm * 4 + i]; b[i] = Bs[kk][tn * 4 + i]; }
#pragma unroll
      for (int i = 0; i < 4; i++)
#pragma unroll
        for (int j = 0; j < 4; j++)
          acc[i][j] = fmaf(a[i], b[j], acc[i][j]);
    }
    __syncthreads();
  }
#pragma unroll
  for (int i = 0; i < 4; i++) {
    int row = m0 + tm * 4 + i;
    if (row >= M) continue;
#pragma unroll
    for (int j = 0; j < 4; j++) {
      int col = n0 + tn * 4 + j;
      if (col >= N) continue;
      long idx = (long)row * ldc + col;
      float v = acc[i][j];
      float o = alpha * v;
      if (bias) o += bias[col];
      C[idx] = (beta != 0.f) ? o + beta * C[idx] : o;
    }
  }
}

// ---------------------------------------------------------------------------
__global__ void cls_copy(const float* __restrict__ c, float* __restrict__ h) {
  h[threadIdx.x] = c[threadIdx.x];
}

__global__ __launch_bounds__(256) void ln_pad_b(const float* __restrict__ h,
    const float* __restrict__ g, const float* __restrict__ b,
    u16* __restrict__ out, int pad)
{
  int s = blockIdx.x, t = threadIdx.x;
  u16* o = out + (long)s * CH;
  if (s < pad) { o[t] = 0; o[t + 256] = 0; return; }
  const float* x = h + (long)(s - pad) * CH;
  float x0 = x[t], x1 = x[t + 256];
  float mu = blockSum(x0 + x1) * (1.f / 512.f);
  float d0 = x0 - mu, d1 = x1 - mu;
  float var = blockSum(d0 * d0 + d1 * d1) * (1.f / 512.f);
  float rs = rsqrtf(var + 1e-5f);
  o[t]       = f2b(d0 * rs * g[t]       + b[t]);
  o[t + 256] = f2b(d1 * rs * g[t + 256] + b[t + 256]);
}

// fused landmark means for q (blocks 0..2047) and k (blocks 2048..4095)
__global__ __launch_bounds__(64) void landmark_b2(const u16* __restrict__ q,
    const u16* __restrict__ k,
    float* __restrict__ ql, float* __restrict__ kl,
    u16* __restrict__ qlb, u16* __restrict__ klb) {
  int isK = blockIdx.x >> 11;
  int hb = blockIdx.x & 2047;
  int d = threadIdx.x;
  int hh = hb >> 8, j = hb & 255;
  const u16* base = isK ? k : q;
  const u16* src = base + ((long)hh * S + (long)j * 65) * 64 + d;
  float s = 0.f;
  for (int g2 = 0; g2 < 65; g2++) s += b2f(src[(long)g2 * 64]);
  s *= (1.f / 65.f);
  float* outf = isK ? kl : ql;
  u16* outb = isK ? klb : qlb;
  outf[(long)hb * 64 + d] = s;
  outb[(long)hb * 64 + d] = f2b(s);
}

__global__ __launch_bounds__(256) void colabs(const float* __restrict__ a2, float* __restrict__ cs) {
  int hb = blockIdx.x; int hh = hb >> 8, j = hb & 255;
  float s = blockSum(fabsf(a2[((long)hh * 256 + threadIdx.x) * 256 + j]));
  if (threadIdx.x == 0) cs[hb] = s;
}
// row-sums of softmax'd a2 are identically 1 -> scale = 1 / max colsum
__global__ __launch_bounds__(256) void scaleinv(const float* __restrict__ cs,
                                                float* __restrict__ inv) {
  float m2 = -1e30f;
  for (int i = threadIdx.x; i < 2048; i += 256) m2 = fmaxf(m2, cs[i]);
  m2 = blockMax(m2);
  if (threadIdx.x == 0) inv[0] = 1.f / m2;
}
__global__ __launch_bounds__(256) void z0k(const float* __restrict__ a2,
                                           const float* __restrict__ inv, float* __restrict__ z) {
  int hb = blockIdx.x; int hh = hb >> 8, i = hb & 255; int j = threadIdx.x;
  z[(long)hb * 256 + j] = a2[((long)hh * 256 + j) * 256 + i] * inv[0];
}

// ---------------------------------------------------------------------------
// LDS-tiled depthwise residual conv (kernel 33, pad 16): Fb += conv(v), bf16.
__global__ __launch_bounds__(256) void resconv2(const u16* __restrict__ v,
    const float* __restrict__ w, u16* __restrict__ Fb)
{
  __shared__ u16 T[160][64];
  __shared__ float ws[33];
  const int hh = blockIdx.y;
  const int p0 = blockIdx.x * 128;
  const int tid = threadIdx.x;
  if (tid < 33) ws[tid] = w[hh * 33 + tid];
  const u16* vh = v + (long)hh * S * 64;
  for (int idx = tid; idx < 640; idx += 256) {
    int row = idx >> 2, seg = (idx & 3) * 16;
    int j = p0 - 16 + row;
    short8_t a = {}, b = {};
    if (0 <= j && j < S) {
      const u16* src = vh + (long)j * 64 + seg;
      a = *(const short8_t*)src; b = *(const short8_t*)(src + 8);
    }
    *(short8_t*)&T[row][seg]     = a;
    *(short8_t*)&T[row][seg + 8] = b;
  }
  __syncthreads();
  const int d = tid & 63;
  const int pg = tid >> 6;
  float wreg[33];
#pragma unroll
  for (int t = 0; t < 33; t++) wreg[t] = ws[t];
#pragma unroll
  for (int g = 0; g < 4; g++) {
    const int base = pg * 32 + g * 8;
    float win[40];
#pragma unroll
    for (int i = 0; i < 40; i++) win[i] = b2f(T[base + i][d]);
#pragma unroll
    for (int p = 0; p < 8; p++) {
      float acc = 0.f;
#pragma unroll
      for (int t = 0; t < 33; t++) acc = fmaf(wreg[t], win[p + t], acc);
      long idx = (long)(p0 + base + p) * CH + hh * 64 + d;
      Fb[idx] = f2b(b2f(Fb[idx]) + acc);
    }
  }
}

// h feat rows (1..16384, 512 cols) -> f (512, 16384) CHW
__global__ __launch_bounds__(256) void transpose_feat(const float* __restrict__ h, float* __restrict__ f) {
  __shared__ float tile[32][33];
  int p0 = blockIdx.x * 32;
  int c0 = blockIdx.y * 32;
  int tx = threadIdx.x & 31, ty = threadIdx.x >> 5;
  for (int i = 0; i < 32; i += 8)
    tile[ty + i][tx] = h[(long)(1 + p0 + ty + i) * CH + c0 + tx];
  __syncthreads();
  for (int i = 0; i < 32; i += 8)
    f[(long)(c0 + ty + i) * 16384 + p0 + tx] = tile[tx][ty + i];
}

// PPEG conv v2: register sliding window, 4 consecutive rows per thread.
__global__ __launch_bounds__(256) void ppeg_tile(const float* __restrict__ f,
    const float* __restrict__ w7, const float* __restrict__ b7,
    const float* __restrict__ w5, const float* __restrict__ b5,
    const float* __restrict__ w3, const float* __restrict__ b3,
    float* __restrict__ fo)
{
  __shared__ float T[38][40];
  __shared__ float W7s[49], W5s[25], W3s[9];
  int c = blockIdx.y;
  int ty0 = (blockIdx.x >> 2) * 32, tx0 = (blockIdx.x & 3) * 32;
  int tid = threadIdx.x;
  if (tid < 49) W7s[tid] = w7[c * 49 + tid];
  if (tid < 25) W5s[tid] = w5[c * 25 + tid];
  if (tid < 9)  W3s[tid] = w3[c * 9 + tid];
  const float* fc = f + (long)c * 16384;
  for (int idx = tid; idx < 38 * 38; idx += 256) {
    int r = idx / 38, cc = idx - r * 38;
    int y = ty0 + r - 3, x = tx0 + cc - 3;
    T[r][cc] = (0 <= y && y < 128 && 0 <= x && x < 128) ? fc[y * 128 + x] : 0.f;
  }
  __syncthreads();
  const int x = tid & 31, y0 = (tid >> 5) * 4;
  float bsum = b7[c] + b5[c] + b3[c];
  float acc[4];
#pragma unroll
  for (int p = 0; p < 4; p++) acc[p] = T[y0 + p + 3][x + 3] + bsum;
#pragma unroll
  for (int dx = 0; dx < 7; dx++) {
    float col[10];
#pragma unroll
    for (int r = 0; r < 10; r++) col[r] = T[y0 + r][x + dx];
#pragma unroll
    for (int dy = 0; dy < 7; dy++) {
      float wv = W7s[dy * 7 + dx];
#pragma unroll
      for (int p = 0; p < 4; p++) acc[p] = fmaf(wv, col[p + dy], acc[p]);
    }
  }
#pragma unroll
  for (int dx = 0; dx < 5; dx++) {
    float col[8];
#pragma unroll
    for (int r = 0; r < 8; r++) col[r] = T[y0 + 1 + r][x + dx + 1];
#pragma unroll
    for (int dy = 0; dy < 5; dy++) {
      float wv = W5s[dy * 5 + dx];
#pragma unroll
      for (int p = 0; p < 4; p++) acc[p] = fmaf(wv, col[p + dy], acc[p]);
    }
  }
#pragma unroll
  for (int dx = 0; dx < 3; dx++) {
    float col[6];
#pragma unroll
    for (int r = 0; r < 6; r++) col[r] = T[y0 + 2 + r][x + dx + 2];
#pragma unroll
    for (int dy = 0; dy < 3; dy++) {
      float wv = W3s[dy * 3 + dx];
#pragma unroll
      for (int p = 0; p < 4; p++) acc[p] = fmaf(wv, col[p + dy], acc[p]);
    }
  }
#pragma unroll
  for (int p = 0; p < 4; p++)
    fo[(long)c * 16384 + (ty0 + y0 + p) * 128 + tx0 + x] = acc[p];
}

// fo (512,16384) CHW -> h rows 1..16384
__global__ __launch_bounds__(256) void transpose_back(const float* __restrict__ fo, float* __restrict__ h) {
  __shared__ float tile[32][33];
  int p0 = blockIdx.x * 32;
  int c0 = blockIdx.y * 32;
  int tx = threadIdx.x & 31, ty = threadIdx.x >> 5;
  for (int i = 0; i < 32; i += 8)
    tile[ty + i][tx] = fo[(long)(c0 + ty + i) * 16384 + p0 + tx];
  __syncthreads();
  for (int i = 0; i < 32; i += 8)
    h[(long)(1 + p0 + ty + i) * CH + c0 + tx] = tile[tx][ty + i];
}

// final: LN(h row 0) then 2-class head
__global__ __launch_bounds__(256) void final_k(const float* __restrict__ h,
    const float* __restrict__ g, const float* __restrict__ b,
    const float* __restrict__ w, const float* __restrict__ fb, float* __restrict__ out)
{
  int t = threadIdx.x;
  float x0 = h[t], x1 = h[t + 256];
  float mu = blockSum(x0 + x1) * (1.f / 512.f);
  float d0 = x0 - mu, d1 = x1 - mu;
  float var = blockSum(d0 * d0 + d1 * d1) * (1.f / 512.f);
  float rs = rsqrtf(var + 1e-5f);
  float y0 = d0 * rs * g[t]       + b[t];
  float y1 = d1 * rs * g[t + 256] + b[t + 256];
  float s0 = blockSum(y0 * w[t]       + y1 * w[t + 256]);
  float s1 = blockSum(y0 * w[512 + t] + y1 * w[512 + t + 256]);
  if (t == 0) {
    out[0] = s0 + fb[0];
    out[1] = s1 + fb[1];
  }
}

// ---------------------------------------------------------------------------
struct AttnW {
  const float *lng, *lnb, *qkvw, *outw, *outb, *resw;
};

static void run_attn(const AttnW& Wt, const u16* qkvw_b, const u16* outw_b,
                     float* h, u16* hn_b, u16* qb, u16* kb, u16* vb, u16* Fb,
                     float* ql, float* kl, u16* qlb, u16* klb,
                     float* w3v, float* Wm, u16* WmT_b,
                     float* a2, float* xz, float* t1, float* t2, float* zA, float* zB,
                     float* cs, float* inv,
                     float* pm, float* pl, float* poacc,
                     hipStream_t stream)
{
  const long s64 = (long)S * 64;
  ln_pad_b<<<S, 256, 0, stream>>>(h, Wt.lng, Wt.lnb, hn_b, PADR);
  mfma_gemm_g<2><<<dim3(12, 130, 1), 256, 0, stream>>>(
      hn_b, qkvw_b, nullptr, nullptr, S, 1536, 512, 512, 512, 0,
      0.125f, 0.f, qb, kb, vb, s64);
  landmark_b2<<<4096, 64, 0, stream>>>(qb, kb, ql, kl, qlb, klb);
  // a2 = softmax(ql @ kl^T) — fused MFMA score+softmax
  a2_fused<<<dim3(4, 8), 256, 0, stream>>>(qlb, klb, a2);
  colabs<<<2048, 256, 0, stream>>>(a2, cs);
  scaleinv<<<1, 256, 0, stream>>>(cs, inv);
  z0k<<<2048, 256, 0, stream>>>(a2, inv, zA);
  float* zc = zA; float* zo = zB;
  for (int it = 0; it < 5; it++) {
    pinv_gemm<3, 0><<<dim3(8, 8, 8), 256, 0, stream>>>(a2, zc, xz, t1, 1.f, 7.f);
    pinv_gemm<4, 0><<<dim3(8, 8, 8), 256, 0, stream>>>(xz, t1, t2, nullptr, 1.f, 15.f);
    pinv_gemm<4, 0><<<dim3(8, 8, 8), 256, 0, stream>>>(xz, t2, t1, nullptr, 1.f, 13.f);
    pinv_gemm<0, 0><<<dim3(8, 8, 8), 256, 0, stream>>>(zc, t1, zo, nullptr, 0.25f, 0.f);
    float* tmp = zc; zc = zo; zo = tmp;
  }
  // final NS iteration at f32-grade (hi/lo) precision
  pinv_gemm<3, 1><<<dim3(8, 8, 8), 256, 0, stream>>>(a2, zc, xz, t1, 1.f, 7.f);
  pinv_gemm<4, 1><<<dim3(8, 8, 8), 256, 0, stream>>>(xz, t1, t2, nullptr, 1.f, 15.f);
  pinv_gemm<4, 1><<<dim3(8, 8, 8), 256, 0, stream>>>(xz, t2, t1, nullptr, 1.f, 13.f);
  pinv_gemm<0, 1><<<dim3(8, 8, 8), 256, 0, stream>>>(zc, t1, zo, nullptr, 0.25f, 0.f);
  { float* tmp = zc; zc = zo; zo = tmp; }
  attn_a3v_split<<<dim3(4, 8, 13), 256, 0, stream>>>(qlb, kb, vb, pm, pl, poacc, s64);
  a3v_merge<<<2048, 64, 0, stream>>>(pm, pl, poacc, w3v);
  mm_kernel<false, 0><<<dim3(1, 4, 8), 256, 0, stream>>>(
      zc, w3v, Wm, nullptr, 256, 64, 256, 256, 64, 64, 65536, 16384, 16384, 1.f, 0.f, 0);
  wm_transpose<<<dim3(64, 8, 1), 256, 0, stream>>>(Wm, WmT_b);
  attn_a1<<<dim3(260, 8, 1), 256, 0, stream>>>(qb, klb, WmT_b, Fb, s64);
  resconv2<<<dim3(130, 8, 1), 256, 0, stream>>>(vb, Wt.resw, Fb);
  // h += Fb[PADR:, :] @ outw^T + outb  (bf16 A via gload_lds)
  mfma_gemm_g<0><<<dim3(4, 129, 1), 256, 0, stream>>>(
      Fb + (long)PADR * CH, outw_b, h, Wt.outb, NT, 512, 512, 512, 512, 512,
      1.f, 1.f, nullptr, nullptr, nullptr, 0);
}

extern "C" void kernel_launch(void* const* d_in, const int* in_sizes, int n_in,
                              void* d_out, int out_size, void* d_ws, size_t ws_size,
                              hipStream_t stream)
{
  const float* X      = (const float*)d_in[0];
  const float* fc1w   = (const float*)d_in[1];
  const float* fc1b   = (const float*)d_in[2];
  const float* clstok = (const float*)d_in[3];
  AttnW w1{ (const float*)d_in[4], (const float*)d_in[5], (const float*)d_in[6],
            (const float*)d_in[7], (const float*)d_in[8], (const float*)d_in[9] };
  const float* w7 = (const float*)d_in[10]; const float* b7 = (const float*)d_in[11];
  const float* w5 = (const float*)d_in[12]; const float* b5 = (const float*)d_in[13];
  const float* w3 = (const float*)d_in[14]; const float* b3 = (const float*)d_in[15];
  AttnW w2{ (const float*)d_in[16], (const float*)d_in[17], (const float*)d_in[18],
            (const float*)d_in[19], (const float*)d_in[20], (const float*)d_in[21] };
  const float* lnfg = (const float*)d_in[22];
  const float* lnfb = (const float*)d_in[23];
  const float* fc2w = (const float*)d_in[24];
  const float* fc2b = (const float*)d_in[25];
  float* out = (float*)d_out;

  char* wsb = (char*)d_ws;
  size_t off = 0;
  auto alloc = [&](size_t nbytes) {
    void* p = wsb + off;
    off = (off + nbytes + 255) & ~(size_t)255;
    return p;
  };
  float* h    = (float*)alloc((size_t)NT * CH * 4);
  float* F    = (float*)alloc((size_t)S * CH * 4);      // ppeg CHW temp (f32)
  u16*  Fb    = (u16*)alloc((size_t)(S + 256) * CH * 2); // attn out bf16 (+slack)
  u16*  hn_b  = (u16*)alloc((size_t)S * CH * 2);
  u16*  qb    = (u16*)alloc((size_t)S * CH * 2);
  u16*  kb    = (u16*)alloc((size_t)S * CH * 2);
  u16*  vb    = (u16*)alloc((size_t)S * CH * 2);
  char* big   = (char*)alloc(33554432);                 // Xb bf16 / ppeg CHW f32
  u16*  fc1w_b = (u16*)alloc(524288 * 2);
  u16*  qkv1_b = (u16*)alloc(786432 * 2);
  u16*  qkv2_b = (u16*)alloc(786432 * 2);
  u16*  out1_b = (u16*)alloc(262144 * 2);
  u16*  out2_b = (u16*)alloc(262144 * 2);
  float* ql   = (float*)alloc(131072 * 4);
  float* kl   = (float*)alloc(131072 * 4);
  u16*  qlb   = (u16*)alloc(131072 * 2);
  u16*  klb   = (u16*)alloc(131072 * 2);
  float* w3v  = (float*)alloc(131072 * 4);
  float* Wm   = (float*)alloc(131072 * 4);
  u16*  WmT_b = (u16*)alloc(131072 * 2);
  float* a2   = (float*)alloc(524288 * 4);
  float* xz   = (float*)alloc(524288 * 4);
  float* t1   = (float*)alloc(524288 * 4);
  float* t2   = (float*)alloc(524288 * 4);
  float* zA   = (float*)alloc(524288 * 4);
  float* zB   = (float*)alloc(524288 * 4);
  float* cs   = (float*)alloc(2048 * 4);
  float* inv  = (float*)alloc(256);
  float* pm   = (float*)alloc((size_t)8 * 13 * 256 * 4);
  float* pl   = (float*)alloc((size_t)8 * 13 * 256 * 4);
  float* poacc = (float*)alloc((size_t)8 * 13 * 256 * 64 * 4);
  (void)in_sizes; (void)n_in; (void)out_size; (void)ws_size;

  // weight conversions
  cvt_f2b<<<512, 256, 0, stream>>>(fc1w, fc1w_b, 524288);
  cvt_f2b<<<768, 256, 0, stream>>>(w1.qkvw, qkv1_b, 786432);
  cvt_f2b<<<768, 256, 0, stream>>>(w2.qkvw, qkv2_b, 786432);
  cvt_f2b<<<256, 256, 0, stream>>>(w1.outw, out1_b, 262144);
  cvt_f2b<<<256, 256, 0, stream>>>(w2.outw, out2_b, 262144);
  // X -> bf16 (big), consumed by fc1 before ppeg reuses big
  u16* Xb = (u16*)big;
  cvt_f2b<<<16384, 256, 0, stream>>>(X, Xb, (long)16384 * 1024);

  cls_copy<<<1, 512, 0, stream>>>(clstok, h);
  mfma_gemm_g<1><<<dim3(4, 128, 1), 256, 0, stream>>>(
      Xb, fc1w_b, h + CH, fc1b, 16384, 512, 1024, 1024, 1024, 512,
      1.f, 0.f, nullptr, nullptr, nullptr, 0);

  run_attn(w1, qkv1_b, out1_b, h, hn_b, qb, kb, vb, Fb, ql, kl, qlb, klb,
           w3v, Wm, WmT_b, a2, xz, t1, t2, zA, zB, cs, inv,
           pm, pl, poacc, stream);

  // PPEG: h -> CHW(big) -> conv -> CHW(F) -> h
  float* fppeg = (float*)big;
  transpose_feat<<<dim3(512, 16, 1), 256, 0, stream>>>(h, fppeg);
  ppeg_tile<<<dim3(16, 512, 1), 256, 0, stream>>>(fppeg, w7, b7, w5, b5, w3, b3, F);
  transpose_back<<<dim3(512, 16, 1), 256, 0, stream>>>(F, h);

  run_attn(w2, qkv2_b, out2_b, h, hn_b, qb, kb, vb, Fb, ql, kl, qlb, klb,
           w3v, Wm, WmT_b, a2, xz, t1, t2, zA, zB, cs, inv,
           pm, pl, poacc, stream);

  final_k<<<1, 256, 0, stream>>>(h, lnfg, lnfb, fc2w, fc2b, out);
}

// Round 17
// 1057.987 us; speedup vs baseline: 1.0266x; 1.0266x over previous
//
#include <hip/hip_runtime.h>
#include <hip/hip_bf16.h>

static const int S    = 16640;  // padded sequence (65*256)
static const int PADR = 255;    // zero rows prepended inside attention
static const int NT   = 16385;  // tokens incl cls
static const int CH   = 512;    // hidden dim

typedef unsigned short u16;
typedef __attribute__((ext_vector_type(8))) short short8_t;
typedef __attribute__((ext_vector_type(4))) float float4_t;

__device__ __forceinline__ float b2f(u16 x) {
  union { unsigned u; float f; } t; t.u = (unsigned)x << 16; return t.f;
}
__device__ __forceinline__ u16 f2b(float x) {
  union { float f; unsigned u; } t; t.f = x;
  unsigned r = t.u + 0x7fff + ((t.u >> 16) & 1);
  return (u16)(r >> 16);
}

// async global->LDS, 16B per lane; LDS dest is wave-uniform base + lane*16
__device__ __forceinline__ void gload_lds16(const u16* g, u16* l) {
  __builtin_amdgcn_global_load_lds(
      (const __attribute__((address_space(1))) unsigned int*)(g),
      (__attribute__((address_space(3))) unsigned int*)(l), 16, 0, 0);
}

__device__ __forceinline__ float warpSum(float v) {
#pragma unroll
  for (int off = 32; off; off >>= 1) v += __shfl_xor(v, off);
  return v;
}
__device__ __forceinline__ float warpMax(float v) {
#pragma unroll
  for (int off = 32; off; off >>= 1) v = fmaxf(v, __shfl_xor(v, off));
  return v;
}
__device__ __forceinline__ float blockSum(float v) {
  __shared__ float sm[8];
  int lane = threadIdx.x & 63, wv = threadIdx.x >> 6;
  v = warpSum(v);
  __syncthreads();
  if (lane == 0) sm[wv] = v;
  __syncthreads();
  float t = 0.f;
  int nw = blockDim.x >> 6;
  for (int i = 0; i < nw; i++) t += sm[i];
  return t;
}
__device__ __forceinline__ float blockMax(float v) {
  __shared__ float sm[8];
  int lane = threadIdx.x & 63, wv = threadIdx.x >> 6;
  v = warpMax(v);
  __syncthreads();
  if (lane == 0) sm[wv] = v;
  __syncthreads();
  float t = -1e30f;
  int nw = blockDim.x >> 6;
  for (int i = 0; i < nw; i++) t = fmaxf(t, sm[i]);
  return t;
}

// ---------------------------------------------------------------------------
__global__ __launch_bounds__(256) void cvt_f2b(const float* __restrict__ in,
                                               u16* __restrict__ out, long n) {
  long i = ((long)blockIdx.x * 256 + threadIdx.x) * 4;
  if (i + 3 < n) {
    float4 v = *(const float4*)(in + i);
    out[i] = f2b(v.x); out[i + 1] = f2b(v.y); out[i + 2] = f2b(v.z); out[i + 3] = f2b(v.w);
  } else {
    for (long j = i; j < n; j++) out[j] = f2b(in[j]);
  }
}

// WmT[head][n(64)][k(256)] bf16 <- Wm[head][k(256)][n(64)] f32
__global__ __launch_bounds__(256) void wm_transpose(const float* __restrict__ Wm,
                                                    u16* __restrict__ WmT) {
  int n = blockIdx.x, head = blockIdx.y, k = threadIdx.x;
  WmT[((long)head * 64 + n) * 256 + k] = f2b(Wm[(long)head * 16384 + k * 64 + n]);
}

// ---------------------------------------------------------------------------
// Generalized gload_lds MFMA GEMM, BK=64 (32 MFMAs per barrier), SINGLE buffer
// (round-16 dbuf regressed: 64KB LDS halved occupancy, barrier still drains
// vmcnt; 2-barrier single-buffer at 2 blocks/CU is this structure's optimum).
// Linear LDS (row = 128B) + 3-bit XOR source/read swizzle. XCD swizzle (T1).
// 128x128 tile, K%64==0, lda/ldb%8==0. A rows beyond M may be read
// (must be in allocation); C-writes masked.
//  EPI 0: C = alpha*acc + bias? + beta*C (f32)
//  EPI 1: C = relu(acc + bias) (f32)
//  EPI 2: qkv head-split bf16 store (q scaled by alpha)
template <int EPI>
__global__ __launch_bounds__(256) void mfma_gemm_g(
    const u16* __restrict__ A, const u16* __restrict__ B, float* __restrict__ C,
    const float* __restrict__ bias, int M, int N, int K,
    int lda, int ldb, int ldc, float alpha, float beta,
    u16* __restrict__ q_o, u16* __restrict__ k_o, u16* __restrict__ v_o, long s64)
{
  __shared__ u16 As[128 * 64];
  __shared__ u16 Bs[128 * 64];
  const int tid = threadIdx.x;
  const int nwg = gridDim.x * gridDim.y;
  int lid = blockIdx.y * gridDim.x + blockIdx.x;
  {
    const int qq = nwg >> 3, rr = nwg & 7;
    const int xcd = lid & 7, loc = lid >> 3;
    lid = (xcd < rr ? xcd * (qq + 1) : rr * (qq + 1) + (xcd - rr) * qq) + loc;
  }
  const int m0 = (lid / gridDim.x) * 128, n0 = (lid % gridDim.x) * 128;
  const int wid = tid >> 6, lane = tid & 63;
  const int wr = wid >> 1, wc = wid & 1;
  const int l15 = lane & 15, l16 = lane >> 4;
  const int r8 = lane >> 3;       // 0..7
  const int slot = lane & 7;      // 0..7 (16B slots per 128B row)
  float4_t acc[4][4] = {};

  for (int k0 = 0; k0 < K; k0 += 64) {
#pragma unroll
    for (int inst = 0; inst < 4; inst++) {
      const int rbase = wid * 32 + inst * 8;
      const int row = rbase + r8;
      const int gslot = slot ^ ((row >> 1) & 7);
      gload_lds16(A + (long)(m0 + row) * lda + k0 + gslot * 8, &As[rbase * 64]);
      gload_lds16(B + (long)(n0 + row) * ldb + k0 + gslot * 8, &Bs[rbase * 64]);
    }
    __syncthreads();
#pragma unroll
    for (int kk = 0; kk < 2; kk++) {
      short8_t af[4], bfr[4];
#pragma unroll
      for (int i = 0; i < 4; i++) {
        int row = wr * 64 + i * 16 + l15;
        af[i] = *(const short8_t*)&As[row * 64 + ((((kk << 2) + l16) ^ ((row >> 1) & 7)) << 3)];
        int rowb = wc * 64 + i * 16 + l15;
        bfr[i] = *(const short8_t*)&Bs[rowb * 64 + ((((kk << 2) + l16) ^ ((rowb >> 1) & 7)) << 3)];
      }
#pragma unroll
      for (int i = 0; i < 4; i++)
#pragma unroll
        for (int j = 0; j < 4; j++)
          acc[i][j] = __builtin_amdgcn_mfma_f32_16x16x32_bf16(af[i], bfr[j], acc[i][j], 0, 0, 0);
    }
    __syncthreads();
  }

#pragma unroll
  for (int mi = 0; mi < 4; mi++) {
#pragma unroll
    for (int ni = 0; ni < 4; ni++) {
#pragma unroll
      for (int j = 0; j < 4; j++) {
        int r = m0 + wr * 64 + mi * 16 + (l16 << 2) + j;
        int c = n0 + wc * 64 + ni * 16 + l15;
        if (r >= M || c >= N) continue;
        float v = acc[mi][ni][j];
        if constexpr (EPI == 0) {
          long idx = (long)r * ldc + c;
          float o = alpha * v;
          if (bias) o += bias[c];
          if (beta != 0.f) o += beta * C[idx];
          C[idx] = o;
        } else if constexpr (EPI == 1) {
          long idx = (long)r * ldc + c;
          C[idx] = fmaxf(v + bias[c], 0.f);
        } else {  // EPI == 2: qkv split
          int sec = c >> 9, hcol = c & 511;
          int head = hcol >> 6, d = hcol & 63;
          u16* dst = (sec == 0) ? q_o : (sec == 1 ? k_o : v_o);
          float o = (sec == 0) ? v * alpha : v;
          dst[(long)head * s64 + (long)r * 64 + d] = f2b(o);
        }
      }
    }
  }
}

// ---------------------------------------------------------------------------
// Newton-Schulz pinv GEMM. 32x32 tile/block, grid (8,8,8).
// PREC=1: bf16 hi/lo split (3 MFMAs, f32-grade). PREC=0: plain bf16 (1 MFMA).
template <int MODE, int PREC>
__global__ __launch_bounds__(256) void pinv_gemm(
    const float* __restrict__ A, const float* __restrict__ B,
    float* __restrict__ C, float* __restrict__ C2, float alpha, float beta)
{
  __shared__ u16 Ah[32][36], Bh[32][36];
  __shared__ u16 Al[PREC ? 32 : 1][36], Bl[PREC ? 32 : 1][36];
  const int tid = threadIdx.x;
  const long zoff = (long)blockIdx.z << 16;
  A += zoff; B += zoff; C += zoff;
  if constexpr (MODE == 3) C2 += zoff;
  const int m0 = blockIdx.y * 32, n0 = blockIdx.x * 32;
  const int wid = tid >> 6, lane = tid & 63;
  const int wr = wid >> 1, wc = wid & 1;
  const int l15 = lane & 15, l16 = lane >> 4;
  const int arow = tid >> 3, acol = (tid & 7) * 4;
  float4_t acc = {};

  for (int k0 = 0; k0 < 256; k0 += 32) {
    {
      float4 va = *(const float4*)(A + (long)(m0 + arow) * 256 + k0 + acol);
      float4 vb = *(const float4*)(B + (long)(k0 + arow) * 256 + n0 + acol);
      float fa[4] = {va.x, va.y, va.z, va.w};
      float fb[4] = {vb.x, vb.y, vb.z, vb.w};
#pragma unroll
      for (int i = 0; i < 4; i++) {
        u16 hi = f2b(fa[i]);
        Ah[arow][acol + i] = hi;
        u16 hj = f2b(fb[i]);
        Bh[acol + i][arow] = hj;
        if constexpr (PREC) {
          Al[arow][acol + i] = f2b(fa[i] - b2f(hi));
          Bl[acol + i][arow] = f2b(fb[i] - b2f(hj));
        }
      }
    }
    __syncthreads();
    short8_t ah = *(const short8_t*)&Ah[wr * 16 + l15][l16 * 8];
    short8_t bh = *(const short8_t*)&Bh[wc * 16 + l15][l16 * 8];
    acc = __builtin_amdgcn_mfma_f32_16x16x32_bf16(ah, bh, acc, 0, 0, 0);
    if constexpr (PREC) {
      short8_t al = *(const short8_t*)&Al[wr * 16 + l15][l16 * 8];
      short8_t bl = *(const short8_t*)&Bl[wc * 16 + l15][l16 * 8];
      acc = __builtin_amdgcn_mfma_f32_16x16x32_bf16(ah, bl, acc, 0, 0, 0);
      acc = __builtin_amdgcn_mfma_f32_16x16x32_bf16(al, bh, acc, 0, 0, 0);
    }
    __syncthreads();
  }

#pragma unroll
  for (int j = 0; j < 4; j++) {
    int r = m0 + wr * 16 + l16 * 4 + j;
    int c = n0 + wc * 16 + l15;
    long idx = (long)r * 256 + c;
    float v = acc[j];
    if constexpr (MODE == 0) {
      C[idx] = alpha * v;
    } else if constexpr (MODE == 3) {
      C[idx] = v;
      C2[idx] = ((r == c) ? beta : 0.f) - v;
    } else {
      C[idx] = ((r == c) ? beta : 0.f) - v;
    }
  }
}

// ---------------------------------------------------------------------------
// Fused a2 = softmax(ql @ kl^T) per head, f32 out. grid (4 row-tiles, 8 heads).
__global__ __launch_bounds__(256) void a2_fused(
    const u16* __restrict__ qlb, const u16* __restrict__ klb,
    float* __restrict__ a2)
{
  __shared__ u16 KW[256 * 72];
  const int tid = threadIdx.x;
  const int w = tid >> 6, lane = tid & 63;
  const int l15 = lane & 15, l16 = lane >> 4;
  const int head = blockIdx.y;
  const int row0 = blockIdx.x * 64 + w * 16;

  const u16* klh = klb + (long)head * 16384;
#pragma unroll
  for (int i = 0; i < 4; i++) {
    int idx = tid + i * 256;
    int row = idx >> 2, seg = (idx & 3) << 4;
    const u16* src = klh + row * 64 + seg;
    *(short8_t*)&KW[row * 72 + seg]     = *(const short8_t*)src;
    *(short8_t*)&KW[row * 72 + seg + 8] = *(const short8_t*)(src + 8);
  }
  short8_t aq[2];
#pragma unroll
  for (int slab = 0; slab < 2; slab++)
    aq[slab] = *(const short8_t*)(qlb + (long)head * 16384 + (long)(row0 + l15) * 64 + slab * 32 + l16 * 8);
  __syncthreads();

  float4_t sacc[16] = {};
#pragma unroll
  for (int nt = 0; nt < 16; nt++)
#pragma unroll
    for (int slab = 0; slab < 2; slab++) {
      short8_t bfr = *(const short8_t*)&KW[(nt * 16 + l15) * 72 + slab * 32 + l16 * 8];
      sacc[nt] = __builtin_amdgcn_mfma_f32_16x16x32_bf16(aq[slab], bfr, sacc[nt], 0, 0, 0);
    }
#pragma unroll
  for (int reg = 0; reg < 4; reg++) {
    float m = -1e30f;
#pragma unroll
    for (int nt = 0; nt < 16; nt++) m = fmaxf(m, sacc[nt][reg]);
#pragma unroll
    for (int mk = 1; mk <= 8; mk <<= 1) m = fmaxf(m, __shfl_xor(m, mk));
    float s = 0.f;
#pragma unroll
    for (int nt = 0; nt < 16; nt++) { float e = __expf(sacc[nt][reg] - m); sacc[nt][reg] = e; s += e; }
#pragma unroll
    for (int mk = 1; mk <= 8; mk <<= 1) s += __shfl_xor(s, mk);
    float rcp = 1.f / s;
#pragma unroll
    for (int nt = 0; nt < 16; nt++)
      a2[(long)head * 65536 + (long)(row0 + 4 * l16 + reg) * 256 + nt * 16 + l15] =
          sacc[nt][reg] * rcp;
  }
}

// ---------------------------------------------------------------------------
// Fused a1 path (LDS-staged), bf16 output into Fb
__global__ __launch_bounds__(256) void attn_a1(
    const u16* __restrict__ qb, const u16* __restrict__ klb,
    const u16* __restrict__ WmT, u16* __restrict__ Fb, long s64)
{
  __shared__ u16 KW[256 * 72];   // 36.9 KB
  __shared__ u16 Ps[64 * 136];   // 17.4 KB
  const int tid = threadIdx.x;
  const int w = tid >> 6, lane = tid & 63;
  const int l15 = lane & 15, l16 = lane >> 4;
  const int head = blockIdx.y;
  const int row0 = blockIdx.x * 64 + w * 16;

  const u16* klh = klb + (long)head * 16384;
#pragma unroll
  for (int i = 0; i < 4; i++) {
    int idx = tid + i * 256;
    int row = idx >> 2, seg = (idx & 3) << 4;
    const u16* src = klh + row * 64 + seg;
    *(short8_t*)&KW[row * 72 + seg]     = *(const short8_t*)src;
    *(short8_t*)&KW[row * 72 + seg + 8] = *(const short8_t*)(src + 8);
  }
  short8_t aq[2];
#pragma unroll
  for (int slab = 0; slab < 2; slab++)
    aq[slab] = *(const short8_t*)(qb + (long)head * s64 + (long)(row0 + l15) * 64 + slab * 32 + l16 * 8);
  __syncthreads();

  float4_t sacc[16] = {};
#pragma unroll
  for (int nt = 0; nt < 16; nt++)
#pragma unroll
    for (int slab = 0; slab < 2; slab++) {
      short8_t bfr = *(const short8_t*)&KW[(nt * 16 + l15) * 72 + slab * 32 + l16 * 8];
      sacc[nt] = __builtin_amdgcn_mfma_f32_16x16x32_bf16(aq[slab], bfr, sacc[nt], 0, 0, 0);
    }
  float rcp[4];
#pragma unroll
  for (int reg = 0; reg < 4; reg++) {
    float m = -1e30f;
#pragma unroll
    for (int nt = 0; nt < 16; nt++) m = fmaxf(m, sacc[nt][reg]);
#pragma unroll
    for (int mk = 1; mk <= 8; mk <<= 1) m = fmaxf(m, __shfl_xor(m, mk));
    float s = 0.f;
#pragma unroll
    for (int nt = 0; nt < 16; nt++) { float e = __expf(sacc[nt][reg] - m); sacc[nt][reg] = e; s += e; }
#pragma unroll
    for (int mk = 1; mk <= 8; mk <<= 1) s += __shfl_xor(s, mk);
    rcp[reg] = 1.f / s;
  }
  __syncthreads();

  const u16* wmh = WmT + (long)head * 16384;
#pragma unroll
  for (int i = 0; i < 4; i++) {
    int idx = tid + i * 256;
    int row = idx >> 4, seg = (idx & 15) << 4;
    const u16* src = wmh + row * 256 + seg;
    *(short8_t*)&KW[row * 264 + seg]     = *(const short8_t*)src;
    *(short8_t*)&KW[row * 264 + seg + 8] = *(const short8_t*)(src + 8);
  }
#pragma unroll
  for (int nt = 0; nt < 8; nt++)
#pragma unroll
    for (int reg = 0; reg < 4; reg++)
      Ps[(w * 16 + 4 * l16 + reg) * 136 + nt * 16 + l15] = f2b(sacc[nt][reg]);
  __syncthreads();

  float4_t oacc[4] = {};
#pragma unroll
  for (int ks = 0; ks < 4; ks++) {
    short8_t pa = *(const short8_t*)&Ps[(w * 16 + l15) * 136 + ks * 32 + l16 * 8];
#pragma unroll
    for (int vt = 0; vt < 4; vt++) {
      short8_t bv = *(const short8_t*)&KW[(vt * 16 + l15) * 264 + ks * 32 + l16 * 8];
      oacc[vt] = __builtin_amdgcn_mfma_f32_16x16x32_bf16(pa, bv, oacc[vt], 0, 0, 0);
    }
  }
#pragma unroll
  for (int nt = 8; nt < 16; nt++)
#pragma unroll
    for (int reg = 0; reg < 4; reg++)
      Ps[(w * 16 + 4 * l16 + reg) * 136 + (nt - 8) * 16 + l15] = f2b(sacc[nt][reg]);
#pragma unroll
  for (int ks = 4; ks < 8; ks++) {
    short8_t pa = *(const short8_t*)&Ps[(w * 16 + l15) * 136 + (ks - 4) * 32 + l16 * 8];
#pragma unroll
    for (int vt = 0; vt < 4; vt++) {
      short8_t bv = *(const short8_t*)&KW[(vt * 16 + l15) * 264 + ks * 32 + l16 * 8];
      oacc[vt] = __builtin_amdgcn_mfma_f32_16x16x32_bf16(pa, bv, oacc[vt], 0, 0, 0);
    }
  }
#pragma unroll
  for (int vt = 0; vt < 4; vt++)
#pragma unroll
    for (int reg = 0; reg < 4; reg++) {
      int r = row0 + 4 * l16 + reg;
      Fb[(long)r * CH + head * 64 + vt * 16 + l15] = f2b(oacc[vt][reg] * rcp[reg]);
    }
}

// ---------------------------------------------------------------------------
// Split-K fused a3@v with K and V both LDS-staged.
__global__ __launch_bounds__(256) void attn_a3v_split(
    const u16* __restrict__ qlb, const u16* __restrict__ kb,
    const u16* __restrict__ vb,
    float* __restrict__ pm, float* __restrict__ pl, float* __restrict__ poacc,
    long s64)
{
  __shared__ u16 Vt[64][136];
  __shared__ u16 Kt[128 * 72];
  __shared__ u16 Ps[4][16][136];
  const int tid = threadIdx.x;
  const int w = tid >> 6, lane = tid & 63;
  const int l15 = lane & 15, l16 = lane >> 4;
  const int head = blockIdx.y;
  const int split = blockIdx.z;
  const int row0 = blockIdx.x * 64 + w * 16;

  short8_t aq[2];
#pragma unroll
  for (int slab = 0; slab < 2; slab++)
    aq[slab] = *(const short8_t*)(qlb + (long)head * 16384 + (long)(row0 + l15) * 64 + slab * 32 + l16 * 8);

  float m[4], l[4];
  float4_t oacc[4] = {};
#pragma unroll
  for (int r = 0; r < 4; r++) { m[r] = -1e30f; l[r] = 0.f; }

  const u16* kh = kb + (long)head * s64;
  const u16* vh = vb + (long)head * s64;
  const int vrow = tid >> 1, vhalf = (tid & 1) * 32;

  const int kt0 = split * 10;
  for (int kt = kt0; kt < kt0 + 10; kt++) {
    const int j0 = kt * 128;
    __syncthreads();
    {
      const u16* src = vh + (long)(j0 + vrow) * 64 + vhalf;
#pragma unroll
      for (int i = 0; i < 32; i++) Vt[vhalf + i][vrow] = src[i];
    }
#pragma unroll
    for (int i = 0; i < 2; i++) {
      int idx = tid + i * 256;
      int row = idx >> 2, seg = (idx & 3) << 4;
      const u16* src = kh + (long)(j0 + row) * 64 + seg;
      *(short8_t*)&Kt[row * 72 + seg]     = *(const short8_t*)src;
      *(short8_t*)&Kt[row * 72 + seg + 8] = *(const short8_t*)(src + 8);
    }
    __syncthreads();
    float4_t sacc[8] = {};
#pragma unroll
    for (int nt = 0; nt < 8; nt++)
#pragma unroll
      for (int slab = 0; slab < 2; slab++) {
        short8_t bfr = *(const short8_t*)&Kt[(nt * 16 + l15) * 72 + slab * 32 + l16 * 8];
        sacc[nt] = __builtin_amdgcn_mfma_f32_16x16x32_bf16(aq[slab], bfr, sacc[nt], 0, 0, 0);
      }
    float scale[4];
#pragma unroll
    for (int reg = 0; reg < 4; reg++) {
      float tm = -1e30f;
#pragma unroll
      for (int nt = 0; nt < 8; nt++) tm = fmaxf(tm, sacc[nt][reg]);
#pragma unroll
      for (int mk = 1; mk <= 8; mk <<= 1) tm = fmaxf(tm, __shfl_xor(tm, mk));
      float nm = fmaxf(m[reg], tm);
      scale[reg] = __expf(m[reg] - nm);
      m[reg] = nm;
      float ts = 0.f;
#pragma unroll
      for (int nt = 0; nt < 8; nt++) {
        float e = __expf(sacc[nt][reg] - nm);
        sacc[nt][reg] = e; ts += e;
      }
#pragma unroll
      for (int mk = 1; mk <= 8; mk <<= 1) ts += __shfl_xor(ts, mk);
      l[reg] = l[reg] * scale[reg] + ts;
#pragma unroll
      for (int vt = 0; vt < 4; vt++) oacc[vt][reg] *= scale[reg];
    }
#pragma unroll
    for (int nt = 0; nt < 8; nt++)
#pragma unroll
      for (int reg = 0; reg < 4; reg++)
        Ps[w][4 * l16 + reg][nt * 16 + l15] = f2b(sacc[nt][reg]);
#pragma unroll
    for (int ks = 0; ks < 4; ks++) {
      short8_t pa = *(const short8_t*)&Ps[w][l15][ks * 32 + l16 * 8];
#pragma unroll
      for (int vt = 0; vt < 4; vt++) {
        short8_t bv = *(const short8_t*)&Vt[vt * 16 + l15][ks * 32 + l16 * 8];
        oacc[vt] = __builtin_amdgcn_mfma_f32_16x16x32_bf16(pa, bv, oacc[vt], 0, 0, 0);
      }
    }
  }
#pragma unroll
  for (int reg = 0; reg < 4; reg++) {
    int r = row0 + 4 * l16 + reg;
    long pidx = ((long)(head * 13 + split) << 8) + r;
    if (l15 == 0) { pm[pidx] = m[reg]; pl[pidx] = l[reg]; }
#pragma unroll
    for (int vt = 0; vt < 4; vt++)
      poacc[(pidx << 6) + vt * 16 + l15] = oacc[vt][reg];
  }
}

// merge split partials
__global__ __launch_bounds__(64) void a3v_merge(const float* __restrict__ pm,
    const float* __restrict__ pl, const float* __restrict__ poacc,
    float* __restrict__ w3v)
{
  int hb = blockIdx.x;
  int head = hb >> 8, row = hb & 255;
  int d = threadIdx.x;
  float M = -1e30f;
  for (int sp = 0; sp < 13; sp++)
    M = fmaxf(M, pm[((long)(head * 13 + sp) << 8) + row]);
  float num = 0.f, den = 0.f;
  for (int sp = 0; sp < 13; sp++) {
    long pidx = ((long)(head * 13 + sp) << 8) + row;
    float sc = __expf(pm[pidx] - M);
    den += pl[pidx] * sc;
    num += poacc[(pidx << 6) + d] * sc;
  }
  w3v[((long)head << 14) + ((long)row << 6) + d] = num / den;
}

// ---------------------------------------------------------------------------
// SIMT f32 tiled matmul (Wm).
template <bool BT, int MODE>
__global__ __launch_bounds__(256) void mm_kernel(
    const float* __restrict__ A, const float* __restrict__ Bm, float* __restrict__ C,
    const float* __restrict__ bias,
    int M, int N, int K, int lda, int ldb, int ldc,
    long sA, long sB, long sC, float alpha, float beta, long s64)
{
  __shared__ float As[16][64];
  __shared__ float Bs[16][64];
  const int bz = blockIdx.z;
  A  += (long)bz * sA;
  Bm += (long)bz * sB;
  C  += (long)bz * sC;
  const int m0 = blockIdx.y * 64, n0 = blockIdx.x * 64;
  const int tid = threadIdx.x;
  const int tm = tid >> 4, tn = tid & 15;
  const int ar = tid >> 2;
  const int ac = (tid & 3) << 2;
  float acc[4][4] = {};
  for (int k0 = 0; k0 < K; k0 += 16) {
#pragma unroll
    for (int i = 0; i < 4; i++) {
      int gm = m0 + ar, gk = k0 + ac + i;
      As[ac + i][ar] = (gm < M && gk < K) ? A[(long)gm * lda + gk] : 0.f;
    }
    if constexpr (BT) {
#pragma unroll
      for (int i = 0; i < 4; i++) {
        int gn = n0 + ar, gk = k0 + ac + i;
        Bs[ac + i][ar] = (gn < N && gk < K) ? Bm[(long)gn * ldb + gk] : 0.f;
      }
    } else {
      int bk = tid >> 4;
      int bn = (tid & 15) << 2;
#pragma unroll
      for (int i = 0; i < 4; i++) {
        int gk = k0 + bk, gn = n0 + bn + i;
        Bs[bk][bn + i] = (gk < K && gn < N) ? Bm[(long)gk * ldb + gn] : 0.f;
      }
    }
    __syncthreads();
#pragma unroll
    for (int kk = 0; kk < 16; kk++) {
      float a[4], b[4];
#pragma unroll
      for (int i = 0; i < 4; i++) { a[i] = As[kk][tm * 4 + i]; b[i] = Bs[kk][tn * 4 + i]; }
#pragma unroll
      for (int i = 0; i < 4; i++)
#pragma unroll
        for (int j = 0; j < 4; j++)
          acc[i][j] = fmaf(a[i], b[j], acc[i][j]);
    }
    __syncthreads();
  }
#pragma unroll
  for (int i = 0; i < 4; i++) {
    int row = m0 + tm * 4 + i;
    if (row >= M) continue;
#pragma unroll
    for (int j = 0; j < 4; j++) {
      int col = n0 + tn * 4 + j;
      if (col >= N) continue;
      long idx = (long)row * ldc + col;
      float v = acc[i][j];
      float o = alpha * v;
      if (bias) o += bias[col];
      C[idx] = (beta != 0.f) ? o + beta * C[idx] : o;
    }
  }
}

// ---------------------------------------------------------------------------
__global__ void cls_copy(const float* __restrict__ c, float* __restrict__ h) {
  h[threadIdx.x] = c[threadIdx.x];
}

__global__ __launch_bounds__(256) void ln_pad_b(const float* __restrict__ h,
    const float* __restrict__ g, const float* __restrict__ b,
    u16* __restrict__ out, int pad)
{
  int s = blockIdx.x, t = threadIdx.x;
  u16* o = out + (long)s * CH;
  if (s < pad) { o[t] = 0; o[t + 256] = 0; return; }
  const float* x = h + (long)(s - pad) * CH;
  float x0 = x[t], x1 = x[t + 256];
  float mu = blockSum(x0 + x1) * (1.f / 512.f);
  float d0 = x0 - mu, d1 = x1 - mu;
  float var = blockSum(d0 * d0 + d1 * d1) * (1.f / 512.f);
  float rs = rsqrtf(var + 1e-5f);
  o[t]       = f2b(d0 * rs * g[t]       + b[t]);
  o[t + 256] = f2b(d1 * rs * g[t + 256] + b[t + 256]);
}

// fused landmark means for q (blocks 0..2047) and k (blocks 2048..4095)
__global__ __launch_bounds__(64) void landmark_b2(const u16* __restrict__ q,
    const u16* __restrict__ k,
    float* __restrict__ ql, float* __restrict__ kl,
    u16* __restrict__ qlb, u16* __restrict__ klb) {
  int isK = blockIdx.x >> 11;
  int hb = blockIdx.x & 2047;
  int d = threadIdx.x;
  int hh = hb >> 8, j = hb & 255;
  const u16* base = isK ? k : q;
  const u16* src = base + ((long)hh * S + (long)j * 65) * 64 + d;
  float s = 0.f;
  for (int g2 = 0; g2 < 65; g2++) s += b2f(src[(long)g2 * 64]);
  s *= (1.f / 65.f);
  float* outf = isK ? kl : ql;
  u16* outb = isK ? klb : qlb;
  outf[(long)hb * 64 + d] = s;
  outb[(long)hb * 64 + d] = f2b(s);
}

__global__ __launch_bounds__(256) void colabs(const float* __restrict__ a2, float* __restrict__ cs) {
  int hb = blockIdx.x; int hh = hb >> 8, j = hb & 255;
  float s = blockSum(fabsf(a2[((long)hh * 256 + threadIdx.x) * 256 + j]));
  if (threadIdx.x == 0) cs[hb] = s;
}
// row-sums of softmax'd a2 are identically 1 -> scale = 1 / max colsum
__global__ __launch_bounds__(256) void scaleinv(const float* __restrict__ cs,
                                                float* __restrict__ inv) {
  float m2 = -1e30f;
  for (int i = threadIdx.x; i < 2048; i += 256) m2 = fmaxf(m2, cs[i]);
  m2 = blockMax(m2);
  if (threadIdx.x == 0) inv[0] = 1.f / m2;
}
__global__ __launch_bounds__(256) void z0k(const float* __restrict__ a2,
                                           const float* __restrict__ inv, float* __restrict__ z) {
  int hb = blockIdx.x; int hh = hb >> 8, i = hb & 255; int j = threadIdx.x;
  z[(long)hb * 256 + j] = a2[((long)hh * 256 + j) * 256 + i] * inv[0];
}

// ---------------------------------------------------------------------------
// LDS-tiled depthwise residual conv (kernel 33, pad 16): Fb += conv(v), bf16.
__global__ __launch_bounds__(256) void resconv2(const u16* __restrict__ v,
    const float* __restrict__ w, u16* __restrict__ Fb)
{
  __shared__ u16 T[160][64];
  __shared__ float ws[33];
  const int hh = blockIdx.y;
  const int p0 = blockIdx.x * 128;
  const int tid = threadIdx.x;
  if (tid < 33) ws[tid] = w[hh * 33 + tid];
  const u16* vh = v + (long)hh * S * 64;
  for (int idx = tid; idx < 640; idx += 256) {
    int row = idx >> 2, seg = (idx & 3) * 16;
    int j = p0 - 16 + row;
    short8_t a = {}, b = {};
    if (0 <= j && j < S) {
      const u16* src = vh + (long)j * 64 + seg;
      a = *(const short8_t*)src; b = *(const short8_t*)(src + 8);
    }
    *(short8_t*)&T[row][seg]     = a;
    *(short8_t*)&T[row][seg + 8] = b;
  }
  __syncthreads();
  const int d = tid & 63;
  const int pg = tid >> 6;
  float wreg[33];
#pragma unroll
  for (int t = 0; t < 33; t++) wreg[t] = ws[t];
#pragma unroll
  for (int g = 0; g < 4; g++) {
    const int base = pg * 32 + g * 8;
    float win[40];
#pragma unroll
    for (int i = 0; i < 40; i++) win[i] = b2f(T[base + i][d]);
#pragma unroll
    for (int p = 0; p < 8; p++) {
      float acc = 0.f;
#pragma unroll
      for (int t = 0; t < 33; t++) acc = fmaf(wreg[t], win[p + t], acc);
      long idx = (long)(p0 + base + p) * CH + hh * 64 + d;
      Fb[idx] = f2b(b2f(Fb[idx]) + acc);
    }
  }
}

// h feat rows (1..16384, 512 cols) -> f (512, 16384) CHW
__global__ __launch_bounds__(256) void transpose_feat(const float* __restrict__ h, float* __restrict__ f) {
  __shared__ float tile[32][33];
  int p0 = blockIdx.x * 32;
  int c0 = blockIdx.y * 32;
  int tx = threadIdx.x & 31, ty = threadIdx.x >> 5;
  for (int i = 0; i < 32; i += 8)
    tile[ty + i][tx] = h[(long)(1 + p0 + ty + i) * CH + c0 + tx];
  __syncthreads();
  for (int i = 0; i < 32; i += 8)
    f[(long)(c0 + ty + i) * 16384 + p0 + tx] = tile[tx][ty + i];
}

// PPEG conv v2: register sliding window, 4 consecutive rows per thread.
__global__ __launch_bounds__(256) void ppeg_tile(const float* __restrict__ f,
    const float* __restrict__ w7, const float* __restrict__ b7,
    const float* __restrict__ w5, const float* __restrict__ b5,
    const float* __restrict__ w3, const float* __restrict__ b3,
    float* __restrict__ fo)
{
  __shared__ float T[38][40];
  __shared__ float W7s[49], W5s[25], W3s[9];
  int c = blockIdx.y;
  int ty0 = (blockIdx.x >> 2) * 32, tx0 = (blockIdx.x & 3) * 32;
  int tid = threadIdx.x;
  if (tid < 49) W7s[tid] = w7[c * 49 + tid];
  if (tid < 25) W5s[tid] = w5[c * 25 + tid];
  if (tid < 9)  W3s[tid] = w3[c * 9 + tid];
  const float* fc = f + (long)c * 16384;
  for (int idx = tid; idx < 38 * 38; idx += 256) {
    int r = idx / 38, cc = idx - r * 38;
    int y = ty0 + r - 3, x = tx0 + cc - 3;
    T[r][cc] = (0 <= y && y < 128 && 0 <= x && x < 128) ? fc[y * 128 + x] : 0.f;
  }
  __syncthreads();
  const int x = tid & 31, y0 = (tid >> 5) * 4;
  float bsum = b7[c] + b5[c] + b3[c];
  float acc[4];
#pragma unroll
  for (int p = 0; p < 4; p++) acc[p] = T[y0 + p + 3][x + 3] + bsum;
#pragma unroll
  for (int dx = 0; dx < 7; dx++) {
    float col[10];
#pragma unroll
    for (int r = 0; r < 10; r++) col[r] = T[y0 + r][x + dx];
#pragma unroll
    for (int dy = 0; dy < 7; dy++) {
      float wv = W7s[dy * 7 + dx];
#pragma unroll
      for (int p = 0; p < 4; p++) acc[p] = fmaf(wv, col[p + dy], acc[p]);
    }
  }
#pragma unroll
  for (int dx = 0; dx < 5; dx++) {
    float col[8];
#pragma unroll
    for (int r = 0; r < 8; r++) col[r] = T[y0 + 1 + r][x + dx + 1];
#pragma unroll
    for (int dy = 0; dy < 5; dy++) {
      float wv = W5s[dy * 5 + dx];
#pragma unroll
      for (int p = 0; p < 4; p++) acc[p] = fmaf(wv, col[p + dy], acc[p]);
    }
  }
#pragma unroll
  for (int dx = 0; dx < 3; dx++) {
    float col[6];
#pragma unroll
    for (int r = 0; r < 6; r++) col[r] = T[y0 + 2 + r][x + dx + 2];
#pragma unroll
    for (int dy = 0; dy < 3; dy++) {
      float wv = W3s[dy * 3 + dx];
#pragma unroll
      for (int p = 0; p < 4; p++) acc[p] = fmaf(wv, col[p + dy], acc[p]);
    }
  }
#pragma unroll
  for (int p = 0; p < 4; p++)
    fo[(long)c * 16384 + (ty0 + y0 + p) * 128 + tx0 + x] = acc[p];
}

// fo (512,16384) CHW -> h rows 1..16384
__global__ __launch_bounds__(256) void transpose_back(const float* __restrict__ fo, float* __restrict__ h) {
  __shared__ float tile[32][33];
  int p0 = blockIdx.x * 32;
  int c0 = blockIdx.y * 32;
  int tx = threadIdx.x & 31, ty = threadIdx.x >> 5;
  for (int i = 0; i < 32; i += 8)
    tile[ty + i][tx] = fo[(long)(c0 + ty + i) * 16384 + p0 + tx];
  __syncthreads();
  for (int i = 0; i < 32; i += 8)
    h[(long)(1 + p0 + ty + i) * CH + c0 + tx] = tile[tx][ty + i];
}

// final: LN(h row 0) then 2-class head
__global__ __launch_bounds__(256) void final_k(const float* __restrict__ h,
    const float* __restrict__ g, const float* __restrict__ b,
    const float* __restrict__ w, const float* __restrict__ fb, float* __restrict__ out)
{
  int t = threadIdx.x;
  float x0 = h[t], x1 = h[t + 256];
  float mu = blockSum(x0 + x1) * (1.f / 512.f);
  float d0 = x0 - mu, d1 = x1 - mu;
  float var = blockSum(d0 * d0 + d1 * d1) * (1.f / 512.f);
  float rs = rsqrtf(var + 1e-5f);
  float y0 = d0 * rs * g[t]       + b[t];
  float y1 = d1 * rs * g[t + 256] + b[t + 256];
  float s0 = blockSum(y0 * w[t]       + y1 * w[t + 256]);
  float s1 = blockSum(y0 * w[512 + t] + y1 * w[512 + t + 256]);
  if (t == 0) {
    out[0] = s0 + fb[0];
    out[1] = s1 + fb[1];
  }
}

// ---------------------------------------------------------------------------
struct AttnW {
  const float *lng, *lnb, *qkvw, *outw, *outb, *resw;
};

static void run_attn(const AttnW& Wt, const u16* qkvw_b, const u16* outw_b,
                     float* h, u16* hn_b, u16* qb, u16* kb, u16* vb, u16* Fb,
                     float* ql, float* kl, u16* qlb, u16* klb,
                     float* w3v, float* Wm, u16* WmT_b,
                     float* a2, float* xz, float* t1, float* t2, float* zA, float* zB,
                     float* cs, float* inv,
                     float* pm, float* pl, float* poacc,
                     hipStream_t stream)
{
  const long s64 = (long)S * 64;
  ln_pad_b<<<S, 256, 0, stream>>>(h, Wt.lng, Wt.lnb, hn_b, PADR);
  mfma_gemm_g<2><<<dim3(12, 130, 1), 256, 0, stream>>>(
      hn_b, qkvw_b, nullptr, nullptr, S, 1536, 512, 512, 512, 0,
      0.125f, 0.f, qb, kb, vb, s64);
  landmark_b2<<<4096, 64, 0, stream>>>(qb, kb, ql, kl, qlb, klb);
  // a2 = softmax(ql @ kl^T) — fused MFMA score+softmax
  a2_fused<<<dim3(4, 8), 256, 0, stream>>>(qlb, klb, a2);
  colabs<<<2048, 256, 0, stream>>>(a2, cs);
  scaleinv<<<1, 256, 0, stream>>>(cs, inv);
  z0k<<<2048, 256, 0, stream>>>(a2, inv, zA);
  float* zc = zA; float* zo = zB;
  for (int it = 0; it < 5; it++) {
    pinv_gemm<3, 0><<<dim3(8, 8, 8), 256, 0, stream>>>(a2, zc, xz, t1, 1.f, 7.f);
    pinv_gemm<4, 0><<<dim3(8, 8, 8), 256, 0, stream>>>(xz, t1, t2, nullptr, 1.f, 15.f);
    pinv_gemm<4, 0><<<dim3(8, 8, 8), 256, 0, stream>>>(xz, t2, t1, nullptr, 1.f, 13.f);
    pinv_gemm<0, 0><<<dim3(8, 8, 8), 256, 0, stream>>>(zc, t1, zo, nullptr, 0.25f, 0.f);
    float* tmp = zc; zc = zo; zo = tmp;
  }
  // final NS iteration at f32-grade (hi/lo) precision
  pinv_gemm<3, 1><<<dim3(8, 8, 8), 256, 0, stream>>>(a2, zc, xz, t1, 1.f, 7.f);
  pinv_gemm<4, 1><<<dim3(8, 8, 8), 256, 0, stream>>>(xz, t1, t2, nullptr, 1.f, 15.f);
  pinv_gemm<4, 1><<<dim3(8, 8, 8), 256, 0, stream>>>(xz, t2, t1, nullptr, 1.f, 13.f);
  pinv_gemm<0, 1><<<dim3(8, 8, 8), 256, 0, stream>>>(zc, t1, zo, nullptr, 0.25f, 0.f);
  { float* tmp = zc; zc = zo; zo = tmp; }
  attn_a3v_split<<<dim3(4, 8, 13), 256, 0, stream>>>(qlb, kb, vb, pm, pl, poacc, s64);
  a3v_merge<<<2048, 64, 0, stream>>>(pm, pl, poacc, w3v);
  mm_kernel<false, 0><<<dim3(1, 4, 8), 256, 0, stream>>>(
      zc, w3v, Wm, nullptr, 256, 64, 256, 256, 64, 64, 65536, 16384, 16384, 1.f, 0.f, 0);
  wm_transpose<<<dim3(64, 8, 1), 256, 0, stream>>>(Wm, WmT_b);
  attn_a1<<<dim3(260, 8, 1), 256, 0, stream>>>(qb, klb, WmT_b, Fb, s64);
  resconv2<<<dim3(130, 8, 1), 256, 0, stream>>>(vb, Wt.resw, Fb);
  // h += Fb[PADR:, :] @ outw^T + outb  (bf16 A via gload_lds)
  mfma_gemm_g<0><<<dim3(4, 129, 1), 256, 0, stream>>>(
      Fb + (long)PADR * CH, outw_b, h, Wt.outb, NT, 512, 512, 512, 512, 512,
      1.f, 1.f, nullptr, nullptr, nullptr, 0);
}

extern "C" void kernel_launch(void* const* d_in, const int* in_sizes, int n_in,
                              void* d_out, int out_size, void* d_ws, size_t ws_size,
                              hipStream_t stream)
{
  const float* X      = (const float*)d_in[0];
  const float* fc1w   = (const float*)d_in[1];
  const float* fc1b   = (const float*)d_in[2];
  const float* clstok = (const float*)d_in[3];
  AttnW w1{ (const float*)d_in[4], (const float*)d_in[5], (const float*)d_in[6],
            (const float*)d_in[7], (const float*)d_in[8], (const float*)d_in[9] };
  const float* w7 = (const float*)d_in[10]; const float* b7 = (const float*)d_in[11];
  const float* w5 = (const float*)d_in[12]; const float* b5 = (const float*)d_in[13];
  const float* w3 = (const float*)d_in[14]; const float* b3 = (const float*)d_in[15];
  AttnW w2{ (const float*)d_in[16], (const float*)d_in[17], (const float*)d_in[18],
            (const float*)d_in[19], (const float*)d_in[20], (const float*)d_in[21] };
  const float* lnfg = (const float*)d_in[22];
  const float* lnfb = (const float*)d_in[23];
  const float* fc2w = (const float*)d_in[24];
  const float* fc2b = (const float*)d_in[25];
  float* out = (float*)d_out;

  char* wsb = (char*)d_ws;
  size_t off = 0;
  auto alloc = [&](size_t nbytes) {
    void* p = wsb + off;
    off = (off + nbytes + 255) & ~(size_t)255;
    return p;
  };
  float* h    = (float*)alloc((size_t)NT * CH * 4);
  float* F    = (float*)alloc((size_t)S * CH * 4);      // ppeg CHW temp (f32)
  u16*  Fb    = (u16*)alloc((size_t)(S + 256) * CH * 2); // attn out bf16 (+slack)
  u16*  hn_b  = (u16*)alloc((size_t)S * CH * 2);
  u16*  qb    = (u16*)alloc((size_t)S * CH * 2);
  u16*  kb    = (u16*)alloc((size_t)S * CH * 2);
  u16*  vb    = (u16*)alloc((size_t)S * CH * 2);
  char* big   = (char*)alloc(33554432);                 // Xb bf16 / ppeg CHW f32
  u16*  fc1w_b = (u16*)alloc(524288 * 2);
  u16*  qkv1_b = (u16*)alloc(786432 * 2);
  u16*  qkv2_b = (u16*)alloc(786432 * 2);
  u16*  out1_b = (u16*)alloc(262144 * 2);
  u16*  out2_b = (u16*)alloc(262144 * 2);
  float* ql   = (float*)alloc(131072 * 4);
  float* kl   = (float*)alloc(131072 * 4);
  u16*  qlb   = (u16*)alloc(131072 * 2);
  u16*  klb   = (u16*)alloc(131072 * 2);
  float* w3v  = (float*)alloc(131072 * 4);
  float* Wm   = (float*)alloc(131072 * 4);
  u16*  WmT_b = (u16*)alloc(131072 * 2);
  float* a2   = (float*)alloc(524288 * 4);
  float* xz   = (float*)alloc(524288 * 4);
  float* t1   = (float*)alloc(524288 * 4);
  float* t2   = (float*)alloc(524288 * 4);
  float* zA   = (float*)alloc(524288 * 4);
  float* zB   = (float*)alloc(524288 * 4);
  float* cs   = (float*)alloc(2048 * 4);
  float* inv  = (float*)alloc(256);
  float* pm   = (float*)alloc((size_t)8 * 13 * 256 * 4);
  float* pl   = (float*)alloc((size_t)8 * 13 * 256 * 4);
  float* poacc = (float*)alloc((size_t)8 * 13 * 256 * 64 * 4);
  (void)in_sizes; (void)n_in; (void)out_size; (void)ws_size;

  // weight conversions
  cvt_f2b<<<512, 256, 0, stream>>>(fc1w, fc1w_b, 524288);
  cvt_f2b<<<768, 256, 0, stream>>>(w1.qkvw, qkv1_b, 786432);
  cvt_f2b<<<768, 256, 0, stream>>>(w2.qkvw, qkv2_b, 786432);
  cvt_f2b<<<256, 256, 0, stream>>>(w1.outw, out1_b, 262144);
  cvt_f2b<<<256, 256, 0, stream>>>(w2.outw, out2_b, 262144);
  // X -> bf16 (big), consumed by fc1 before ppeg reuses big
  u16* Xb = (u16*)big;
  cvt_f2b<<<16384, 256, 0, stream>>>(X, Xb, (long)16384 * 1024);

  cls_copy<<<1, 512, 0, stream>>>(clstok, h);
  mfma_gemm_g<1><<<dim3(4, 128, 1), 256, 0, stream>>>(
      Xb, fc1w_b, h + CH, fc1b, 16384, 512, 1024, 1024, 1024, 512,
      1.f, 0.f, nullptr, nullptr, nullptr, 0);

  run_attn(w1, qkv1_b, out1_b, h, hn_b, qb, kb, vb, Fb, ql, kl, qlb, klb,
           w3v, Wm, WmT_b, a2, xz, t1, t2, zA, zB, cs, inv,
           pm, pl, poacc, stream);

  // PPEG: h -> CHW(big) -> conv -> CHW(F) -> h
  float* fppeg = (float*)big;
  transpose_feat<<<dim3(512, 16, 1), 256, 0, stream>>>(h, fppeg);
  ppeg_tile<<<dim3(16, 512, 1), 256, 0, stream>>>(fppeg, w7, b7, w5, b5, w3, b3, F);
  transpose_back<<<dim3(512, 16, 1), 256, 0, stream>>>(F, h);

  run_attn(w2, qkv2_b, out2_b, h, hn_b, qb, kb, vb, Fb, ql, kl, qlb, klb,
           w3v, Wm, WmT_b, a2, xz, t1, t2, zA, zB, cs, inv,
           pm, pl, poacc, stream);

  final_k<<<1, 256, 0, stream>>>(h, lnfg, lnfb, fc2w, fc2b, out);
}